// Round 2
// baseline (140.975 us; speedup 1.0000x reference)
//
#include <hip/hip_runtime.h>
#include <math.h>

#ifndef M_PI
#define M_PI 3.14159265358979323846
#endif

namespace {
constexpr int kNSamples = 524288;
constexpr int kNGrains  = 4096;
constexpr int kGrainN   = 16384;
constexpr int kTile     = 512;
constexpr int kNTiles   = kNSamples / kTile;  // 1024

// ws layout (bytes), all 8-aligned
constexpr size_t GAMMA_OFF = 0;                            // double
constexpr size_t SCALE_OFF = 8;                            // double (1/norm)
constexpr size_t PART_OFF  = 16;                           // double[kNTiles]
constexpr size_t ONS_OFF   = PART_OFF + 8 * kNTiles;       // int[kNGrains]
constexpr size_t CG_OFF    = ONS_OFF + 4 * kNGrains;       // float[kNGrains]
constexpr size_t F0D_OFF   = CG_OFF + 4 * kNGrains;        // double[kNGrains]
constexpr size_t P_OFF     = F0D_OFF + 8 * kNGrains;       // double[kGrainN]
// end = P_OFF + 8*kGrainN = 204816 bytes
}  // namespace

// Kernel 1: amplitudes (+max), gamma, bitonic sort of (onset, grain idx),
// gather sorted onset/f0(double)/coef arrays into ws.
__global__ __launch_bounds__(1024) void k_setup(const float* __restrict__ dens_p,
                                                const float* __restrict__ slope_p,
                                                const float* __restrict__ f0,
                                                const int* __restrict__ onsets,
                                                void* wsv) {
  char* ws = (char*)wsv;
  __shared__ int   skey[kNGrains];
  __shared__ int   sidx[kNGrains];
  __shared__ float samps[kNGrains];
  __shared__ float red[1024];
  const int tid = threadIdx.x;

  const double d = (double)dens_p[0];
  const double offset = 0.25 * d + 0.75 * d * d;
  for (int g = tid; g < kNGrains; g += 1024) {
    double sig_op = (1.0 - d) * (double)kNGrains * ((double)g / (double)kNGrains - offset);
    // amps = 1 - sigmoid(2*sig_op) = 1/(1+exp(2*sig_op))
    double a = 1.0 / (1.0 + exp(2.0 * sig_op));
    samps[g] = (float)a;
    skey[g]  = onsets[g];
    sidx[g]  = g;
  }
  __syncthreads();

  // max(amps) reduction
  float m = 0.0f;
  for (int g = tid; g < kNGrains; g += 1024) m = fmaxf(m, samps[g]);
  red[tid] = m;
  __syncthreads();
  for (int s = 512; s > 0; s >>= 1) {
    if (tid < s) red[tid] = fmaxf(red[tid], red[tid + s]);
    __syncthreads();
  }
  const float maxamp = red[0];

  if (tid == 0) {
    double ts = (double)slope_p[0];
    double typical_slope = 44100.0 / (12.0 * 256.0);  // 14.35546875 exact
    double gam = tan(ts * M_PI / 2.0) * typical_slope / 4.0;
    *(double*)(ws + GAMMA_OFF) = gam;
  }

  // bitonic sort of 4096 (key=onset, payload=idx)
  for (int kk = 2; kk <= kNGrains; kk <<= 1) {
    for (int j = kk >> 1; j > 0; j >>= 1) {
      __syncthreads();
      for (int t = tid; t < kNGrains; t += 1024) {
        int ixj = t ^ j;
        if (ixj > t) {
          bool up = ((t & kk) == 0);
          int k0 = skey[t], k1 = skey[ixj];
          if ((k0 > k1) == up) {
            skey[t] = k1; skey[ixj] = k0;
            int tmp = sidx[t]; sidx[t] = sidx[ixj]; sidx[ixj] = tmp;
          }
        }
      }
    }
  }
  __syncthreads();

  int*    ons_s = (int*)(ws + ONS_OFF);
  float*  cg_s  = (float*)(ws + CG_OFF);
  double* f0d_s = (double*)(ws + F0D_OFF);
  for (int t = tid; t < kNGrains; t += 1024) {
    int g = sidx[t];
    ons_s[t] = skey[t];
    float f0g = f0[g];
    cg_s[t]  = (samps[g] / maxamp) / sqrtf(f0g);
    f0d_s[t] = (double)f0g;
  }
}

// Kernel 2: phase table in f64. phase = expm1(gamma*t)/gamma (t matches ref's f32 t)
__global__ void k_phase(void* wsv) {
  char* ws = (char*)wsv;
  const int l = blockIdx.x * 256 + threadIdx.x;
  const double gamma = *(const double*)(ws + GAMMA_OFF);
  const float tf = (float)l / 44100.0f - 0.18575963718820862f;  // arange/SR - dur/2
  double ph;
  if (gamma == 0.0) ph = (double)tf;
  else              ph = expm1(gamma * (double)tf) / gamma;
  ((double*)(ws + P_OFF))[l] = ph;
}

// Kernel 3: output-stationary accumulation. Each block owns kTile samples.
__global__ __launch_bounds__(256) void k_main(void* wsv, float* __restrict__ out) {
  char* ws = (char*)wsv;
  const int*    __restrict__ ons  = (const int*)(ws + ONS_OFF);
  const float*  __restrict__ cg   = (const float*)(ws + CG_OFF);
  const double* __restrict__ f0d  = (const double*)(ws + F0D_OFF);
  const double* __restrict__ P    = (const double*)(ws + P_OFF);
  double* __restrict__ partials   = (double*)(ws + PART_OFF);

  const int tile = blockIdx.x;
  const int s    = tile * kTile;
  const int tid  = threadIdx.x;

  // contiguous overlapping-grain range in sorted order:
  // lo = first idx with onset > s - kGrainN ; hi = first idx with onset > s + kTile - 1
  int lo, hi;
  {
    int a = 0, b = kNGrains;
    const int t1 = s - kGrainN;
    while (a < b) { int mid = (a + b) >> 1; if (ons[mid] > t1) b = mid; else a = mid + 1; }
    lo = a;
    a = lo; b = kNGrains;
    const int t2 = s + kTile - 1;
    while (a < b) { int mid = (a + b) >> 1; if (ons[mid] > t2) b = mid; else a = mid + 1; }
    hi = a;
  }
  lo = __builtin_amdgcn_readfirstlane(lo);
  hi = __builtin_amdgcn_readfirstlane(hi);

  float acc0 = 0.0f, acc1 = 0.0f;
  const int i0 = s + tid;
  const int i1 = i0 + 256;

  for (int g = lo; g < hi; ++g) {
    const int    onset = ons[g];
    const double f0    = f0d[g];
    const float  c     = cg[g];
    {
      const int l = i0 - onset;
      if ((unsigned)l < (unsigned)kGrainN) {
        double r  = f0 * P[l];
        float  fr = (float)(r - floor(r));               // fractional revolutions
        float  sv = __builtin_amdgcn_sinf(fr);           // sin(2*pi*fr)
        float  w  = __builtin_amdgcn_sinf((float)l * (1.0f / 32768.0f));  // sin(pi*l/L)
        acc0 = fmaf(c * (w * w), sv, acc0);
      }
    }
    {
      const int l = i1 - onset;
      if ((unsigned)l < (unsigned)kGrainN) {
        double r  = f0 * P[l];
        float  fr = (float)(r - floor(r));
        float  sv = __builtin_amdgcn_sinf(fr);
        float  w  = __builtin_amdgcn_sinf((float)l * (1.0f / 32768.0f));
        acc1 = fmaf(c * (w * w), sv, acc1);
      }
    }
  }

  out[i0] = acc0;
  out[i1] = acc1;

  // fused per-tile sum of squares (f64)
  double p2 = (double)acc0 * (double)acc0 + (double)acc1 * (double)acc1;
  for (int off = 32; off > 0; off >>= 1) p2 += __shfl_down(p2, off);
  __shared__ double wpart[4];
  if ((tid & 63) == 0) wpart[tid >> 6] = p2;
  __syncthreads();
  if (tid == 0) partials[tile] = wpart[0] + wpart[1] + wpart[2] + wpart[3];
}

// Kernel 4: reduce partials -> 1/sqrt(sum)
__global__ __launch_bounds__(256) void k_final(void* wsv) {
  char* ws = (char*)wsv;
  const double* __restrict__ partials = (const double*)(ws + PART_OFF);
  __shared__ double red[256];
  const int tid = threadIdx.x;
  double sum = 0.0;
  for (int t = tid; t < kNTiles; t += 256) sum += partials[t];
  red[tid] = sum;
  __syncthreads();
  for (int s = 128; s > 0; s >>= 1) {
    if (tid < s) red[tid] += red[tid + s];
    __syncthreads();
  }
  if (tid == 0) *(double*)(ws + SCALE_OFF) = 1.0 / sqrt(red[0]);
}

// Kernel 5: scale output by 1/norm (float4)
__global__ __launch_bounds__(256) void k_scale(const void* wsv, float4* __restrict__ out) {
  const float sc = (float)(*(const double*)((const char*)wsv + SCALE_OFF));
  const int i = blockIdx.x * 256 + threadIdx.x;
  float4 v = out[i];
  v.x *= sc; v.y *= sc; v.z *= sc; v.w *= sc;
  out[i] = v;
}

extern "C" void kernel_launch(void* const* d_in, const int* in_sizes, int n_in,
                              void* d_out, int out_size, void* d_ws, size_t ws_size,
                              hipStream_t stream) {
  const float* dens   = (const float*)d_in[0];
  const float* slope  = (const float*)d_in[1];
  const float* f0     = (const float*)d_in[2];
  const int*   onsets = (const int*)d_in[3];
  float* out = (float*)d_out;

  hipLaunchKernelGGL(k_setup, dim3(1), dim3(1024), 0, stream, dens, slope, f0, onsets, d_ws);
  hipLaunchKernelGGL(k_phase, dim3(kGrainN / 256), dim3(256), 0, stream, d_ws);
  hipLaunchKernelGGL(k_main,  dim3(kNTiles), dim3(256), 0, stream, d_ws, out);
  hipLaunchKernelGGL(k_final, dim3(1), dim3(256), 0, stream, d_ws);
  hipLaunchKernelGGL(k_scale, dim3(kNSamples / 1024), dim3(256), 0, stream, d_ws,
                     (float4*)out);
}

// Round 3
// 93.461 us; speedup vs baseline: 1.5084x; 1.5084x over previous
//
#include <hip/hip_runtime.h>
#include <math.h>

#ifndef M_PI
#define M_PI 3.14159265358979323846
#endif

namespace {
constexpr int kNSamples = 524288;
constexpr int kNGrains  = 4096;
constexpr int kGrainN   = 16384;
constexpr int kTile     = 512;
constexpr int kNTiles   = kNSamples / kTile;  // 1024

// ws layout (bytes), all 8-aligned
constexpr size_t GAMMA_OFF = 0;                            // double
constexpr size_t SCALE_OFF = 8;                            // double (1/norm)
constexpr size_t PART_OFF  = 16;                           // double[kNTiles]
constexpr size_t ONS_OFF   = PART_OFF + 8 * kNTiles;       // int[kNGrains]
constexpr size_t CG_OFF    = ONS_OFF + 4 * kNGrains;       // float[kNGrains]
constexpr size_t F0D_OFF   = CG_OFF + 4 * kNGrains;        // double[kNGrains]
constexpr size_t P_OFF     = F0D_OFF + 8 * kNGrains;       // double[kGrainN]
// end = P_OFF + 8*kGrainN = 204816 bytes
}  // namespace

// Kernel 1 (parallel rank sort + per-grain coefs):
// 64 blocks x 256 threads. Block b owns grains [b*64, b*64+64).
// Thread t: grain gi = t&63, key-chunk ck = t>>6 (1024 keys each).
// rank[g] = #{h : (onset[h], h) < (onset[g], g)}  -- strict total order,
// deterministic, no atomics. Then 64 threads scatter amp/f0/onset to sorted
// position. max(amps) == amps[0] in closed form (amps strictly decreasing).
__global__ __launch_bounds__(256) void k_prep(const float* __restrict__ dens_p,
                                              const float* __restrict__ slope_p,
                                              const float* __restrict__ f0,
                                              const int* __restrict__ onsets,
                                              void* wsv) {
  char* ws = (char*)wsv;
  __shared__ int sons[kNGrains];        // 16 KB
  __shared__ int srank[64][5];          // padded
  const int tid = threadIdx.x;

  for (int i = tid; i < kNGrains; i += 256) sons[i] = onsets[i];
  __syncthreads();

  const int gi = tid & 63;
  const int g  = blockIdx.x * 64 + gi;
  const int ck = tid >> 6;              // 0..3
  const int og = sons[g];

  int pr = 0;
  const int h0 = ck * 1024;
#pragma unroll 8
  for (int h = h0; h < h0 + 1024; ++h) {
    const int oh = sons[h];
    pr += (int)(oh < og) | ((int)(oh == og) & (int)(h < g));
  }
  srank[gi][ck] = pr;
  __syncthreads();

  if (tid < 64) {
    const int gg   = blockIdx.x * 64 + tid;
    const int rank = srank[tid][0] + srank[tid][1] + srank[tid][2] + srank[tid][3];

    const double d      = (double)dens_p[0];
    const double offset = 0.25 * d + 0.75 * d * d;
    const double c2     = 2.0 * (1.0 - d) * 4096.0;
    const double amp    = 1.0 / (1.0 + exp(c2 * ((double)gg / 4096.0 - offset)));
    const double amp0   = 1.0 / (1.0 + exp(c2 * (0.0 - offset)));  // max amp

    const float f0g = f0[gg];
    ((int*)(ws + ONS_OFF))[rank]    = sons[gg];
    ((float*)(ws + CG_OFF))[rank]   = (float)(amp / amp0) / sqrtf(f0g);
    ((double*)(ws + F0D_OFF))[rank] = (double)f0g;
  }

  if (blockIdx.x == 0 && tid == 0) {
    const double ts = (double)slope_p[0];
    const double typical_slope = 44100.0 / (12.0 * 256.0);  // 14.35546875 exact
    *(double*)(ws + GAMMA_OFF) = tan(ts * M_PI / 2.0) * typical_slope / 4.0;
  }
}

// Kernel 2: phase table in f64. phase = expm1(gamma*t)/gamma (t matches ref's f32 t)
__global__ void k_phase(void* wsv) {
  char* ws = (char*)wsv;
  const int l = blockIdx.x * 256 + threadIdx.x;
  const double gamma = *(const double*)(ws + GAMMA_OFF);
  const float tf = (float)l / 44100.0f - 0.18575963718820862f;  // arange/SR - dur/2
  double ph;
  if (gamma == 0.0) ph = (double)tf;
  else              ph = expm1(gamma * (double)tf) / gamma;
  ((double*)(ws + P_OFF))[l] = ph;
}

// Kernel 3: output-stationary accumulation. Each block owns kTile samples.
__global__ __launch_bounds__(256) void k_main(void* wsv, float* __restrict__ out) {
  char* ws = (char*)wsv;
  const int*    __restrict__ ons  = (const int*)(ws + ONS_OFF);
  const float*  __restrict__ cg   = (const float*)(ws + CG_OFF);
  const double* __restrict__ f0d  = (const double*)(ws + F0D_OFF);
  const double* __restrict__ P    = (const double*)(ws + P_OFF);
  double* __restrict__ partials   = (double*)(ws + PART_OFF);

  const int tile = blockIdx.x;
  const int s    = tile * kTile;
  const int tid  = threadIdx.x;

  // contiguous overlapping-grain range in sorted order:
  // lo = first idx with onset > s - kGrainN ; hi = first idx with onset > s + kTile - 1
  int lo, hi;
  {
    int a = 0, b = kNGrains;
    const int t1 = s - kGrainN;
    while (a < b) { int mid = (a + b) >> 1; if (ons[mid] > t1) b = mid; else a = mid + 1; }
    lo = a;
    a = lo; b = kNGrains;
    const int t2 = s + kTile - 1;
    while (a < b) { int mid = (a + b) >> 1; if (ons[mid] > t2) b = mid; else a = mid + 1; }
    hi = a;
  }
  lo = __builtin_amdgcn_readfirstlane(lo);
  hi = __builtin_amdgcn_readfirstlane(hi);

  float acc0 = 0.0f, acc1 = 0.0f;
  const int i0 = s + tid;
  const int i1 = i0 + 256;

  for (int g = lo; g < hi; ++g) {
    const int    onset = ons[g];
    const double f0    = f0d[g];
    const float  c     = cg[g];
    {
      const int l = i0 - onset;
      if ((unsigned)l < (unsigned)kGrainN) {
        double r  = f0 * P[l];
        float  fr = (float)(r - floor(r));               // fractional revolutions
        float  sv = __builtin_amdgcn_sinf(fr);           // sin(2*pi*fr)
        float  w  = __builtin_amdgcn_sinf((float)l * (1.0f / 32768.0f));  // sin(pi*l/L)
        acc0 = fmaf(c * (w * w), sv, acc0);
      }
    }
    {
      const int l = i1 - onset;
      if ((unsigned)l < (unsigned)kGrainN) {
        double r  = f0 * P[l];
        float  fr = (float)(r - floor(r));
        float  sv = __builtin_amdgcn_sinf(fr);
        float  w  = __builtin_amdgcn_sinf((float)l * (1.0f / 32768.0f));
        acc1 = fmaf(c * (w * w), sv, acc1);
      }
    }
  }

  out[i0] = acc0;
  out[i1] = acc1;

  // fused per-tile sum of squares (f64)
  double p2 = (double)acc0 * (double)acc0 + (double)acc1 * (double)acc1;
  for (int off = 32; off > 0; off >>= 1) p2 += __shfl_down(p2, off);
  __shared__ double wpart[4];
  if ((tid & 63) == 0) wpart[tid >> 6] = p2;
  __syncthreads();
  if (tid == 0) partials[tile] = wpart[0] + wpart[1] + wpart[2] + wpart[3];
}

// Kernel 4: reduce partials -> 1/sqrt(sum)
__global__ __launch_bounds__(256) void k_final(void* wsv) {
  char* ws = (char*)wsv;
  const double* __restrict__ partials = (const double*)(ws + PART_OFF);
  __shared__ double red[256];
  const int tid = threadIdx.x;
  double sum = 0.0;
  for (int t = tid; t < kNTiles; t += 256) sum += partials[t];
  red[tid] = sum;
  __syncthreads();
  for (int s = 128; s > 0; s >>= 1) {
    if (tid < s) red[tid] += red[tid + s];
    __syncthreads();
  }
  if (tid == 0) *(double*)(ws + SCALE_OFF) = 1.0 / sqrt(red[0]);
}

// Kernel 5: scale output by 1/norm (float4)
__global__ __launch_bounds__(256) void k_scale(const void* wsv, float4* __restrict__ out) {
  const float sc = (float)(*(const double*)((const char*)wsv + SCALE_OFF));
  const int i = blockIdx.x * 256 + threadIdx.x;
  float4 v = out[i];
  v.x *= sc; v.y *= sc; v.z *= sc; v.w *= sc;
  out[i] = v;
}

extern "C" void kernel_launch(void* const* d_in, const int* in_sizes, int n_in,
                              void* d_out, int out_size, void* d_ws, size_t ws_size,
                              hipStream_t stream) {
  const float* dens   = (const float*)d_in[0];
  const float* slope  = (const float*)d_in[1];
  const float* f0     = (const float*)d_in[2];
  const int*   onsets = (const int*)d_in[3];
  float* out = (float*)d_out;

  hipLaunchKernelGGL(k_prep,  dim3(64), dim3(256), 0, stream, dens, slope, f0, onsets, d_ws);
  hipLaunchKernelGGL(k_phase, dim3(kGrainN / 256), dim3(256), 0, stream, d_ws);
  hipLaunchKernelGGL(k_main,  dim3(kNTiles), dim3(256), 0, stream, d_ws, out);
  hipLaunchKernelGGL(k_final, dim3(1), dim3(256), 0, stream, d_ws);
  hipLaunchKernelGGL(k_scale, dim3(kNSamples / 1024), dim3(256), 0, stream, d_ws,
                     (float4*)out);
}

// Round 4
// 84.058 us; speedup vs baseline: 1.6771x; 1.1119x over previous
//
#include <hip/hip_runtime.h>
#include <math.h>

#ifndef M_PI
#define M_PI 3.14159265358979323846
#endif

namespace {
constexpr int kNSamples = 524288;
constexpr int kNGrains  = 4096;
constexpr int kGrainN   = 16384;
constexpr int kTile     = 1024;                 // 4 samples/thread * 256 threads
constexpr int kNTiles   = kNSamples / kTile;    // 512

// ws layout (bytes), all 16-aligned
constexpr size_t PART_OFF  = 0;                            // double[kNTiles]      4 KB
constexpr size_t ONS_OFF   = PART_OFF + 8 * kNTiles;       // int[kNGrains]       16 KB
constexpr size_t GR_OFF    = ONS_OFF + 4 * kNGrains;       // float4[kNGrains]    64 KB
constexpr size_t TAB_OFF   = GR_OFF + 16 * kNGrains;       // float2[kGrainN]    128 KB
constexpr size_t SCALE_OFF = TAB_OFF + 8 * kGrainN;        // double
// end = SCALE_OFF + 8 = 217,096 bytes
}  // namespace

// Kernel 1 (parallel rank sort + per-grain coefs):
// 64 blocks x 256 threads. Block b owns grains [b*64, b*64+64).
// rank[g] = #{h : (onset[h], h) < (onset[g], g)} -- strict total order,
// deterministic, no atomics. max(amps) == amps[0] (amps strictly decreasing).
__global__ __launch_bounds__(256) void k_prep(const float* __restrict__ dens_p,
                                              const float* __restrict__ f0,
                                              const int* __restrict__ onsets,
                                              void* wsv) {
  char* ws = (char*)wsv;
  __shared__ int sons[kNGrains];        // 16 KB
  __shared__ int srank[64][5];          // padded
  const int tid = threadIdx.x;

  for (int i = tid; i < kNGrains; i += 256) sons[i] = onsets[i];
  __syncthreads();

  const int gi = tid & 63;
  const int g  = blockIdx.x * 64 + gi;
  const int ck = tid >> 6;              // 0..3
  const int og = sons[g];

  int pr = 0;
  const int h0 = ck * 1024;
#pragma unroll 8
  for (int h = h0; h < h0 + 1024; ++h) {
    const int oh = sons[h];
    pr += (int)(oh < og) | ((int)(oh == og) & (int)(h < g));
  }
  srank[gi][ck] = pr;
  __syncthreads();

  if (tid < 64) {
    const int gg   = blockIdx.x * 64 + tid;
    const int rank = srank[tid][0] + srank[tid][1] + srank[tid][2] + srank[tid][3];

    const double d      = (double)dens_p[0];
    const double offset = 0.25 * d + 0.75 * d * d;
    const double c2     = 2.0 * (1.0 - d) * 4096.0;
    const double amp    = 1.0 / (1.0 + exp(c2 * ((double)gg / 4096.0 - offset)));
    const double amp0   = 1.0 / (1.0 + exp(c2 * (0.0 - offset)));  // max amp

    const float f0g = f0[gg];
    const float cg  = (float)(amp / amp0) / sqrtf(f0g);
    ((int*)(ws + ONS_OFF))[rank] = sons[gg];
    ((float4*)(ws + GR_OFF))[rank] =
        make_float4(__int_as_float(sons[gg]), f0g, cg, 0.0f);
  }
}

// Kernel 2: tables in f64 -> f32. TAB[l] = { (float)phase_l, sin^2(pi*l/L) }
// gamma recomputed locally per block (cheap, removes cross-kernel dependency).
__global__ __launch_bounds__(256) void k_tables(const float* __restrict__ slope_p,
                                                void* wsv) {
  char* ws = (char*)wsv;
  const int l = blockIdx.x * 256 + threadIdx.x;
  const double ts    = (double)slope_p[0];
  const double gamma = tan(ts * M_PI / 2.0) * (44100.0 / (12.0 * 256.0)) / 4.0;
  const float  tf    = (float)l / 44100.0f - 0.18575963718820862f;  // matches ref f32 t
  double ph;
  if (gamma == 0.0) ph = (double)tf;
  else              ph = expm1(gamma * (double)tf) / gamma;
  const double wv = sin(M_PI * ((double)l / 16384.0));
  ((float2*)(ws + TAB_OFF))[l] = make_float2((float)ph, (float)(wv * wv));
}

// Kernel 3: output-stationary accumulation, all-f32 hot loop.
__global__ __launch_bounds__(256) void k_main(void* wsv, float* __restrict__ out) {
  char* ws = (char*)wsv;
  const int*    __restrict__ ons = (const int*)(ws + ONS_OFF);
  const float4* __restrict__ GR  = (const float4*)(ws + GR_OFF);
  const float2* __restrict__ TAB = (const float2*)(ws + TAB_OFF);
  double* __restrict__ partials  = (double*)(ws + PART_OFF);

  const int tile = blockIdx.x;
  const int s    = tile * kTile;
  const int tid  = threadIdx.x;

  // grains overlapping [s, s+kTile): onset in (s - kGrainN, s + kTile - 1]
  int lo, hi;
  {
    int a = 0, b = kNGrains;
    const int t1 = s - kGrainN;
    while (a < b) { int mid = (a + b) >> 1; if (ons[mid] > t1) b = mid; else a = mid + 1; }
    lo = a;
    a = lo; b = kNGrains;
    const int t2 = s + kTile - 1;
    while (a < b) { int mid = (a + b) >> 1; if (ons[mid] > t2) b = mid; else a = mid + 1; }
    hi = a;
  }
  lo = __builtin_amdgcn_readfirstlane(lo);
  hi = __builtin_amdgcn_readfirstlane(hi);

  float a0 = 0.0f, a1 = 0.0f, a2 = 0.0f, a3 = 0.0f;
  const int base = s + tid;

  float4 grn = GR[lo < kNGrains ? lo : kNGrains - 1];  // prefetch g=lo
  for (int g = lo; g < hi; ++g) {
    const float4 gr = grn;
    const int gnext = (g + 1 < hi) ? g + 1 : g;        // uniform
    grn = GR[gnext];                                    // prefetch g+1

    const int   onset = __float_as_int(gr.x);
    const float f0    = gr.y;
    const float c     = gr.z;
    const int   l0    = base - onset;

#pragma unroll
    for (int k = 0; k < 4; ++k) {
      const int l  = l0 + k * 256;
      const int lc = min(max(l, 0), kGrainN - 1);
      const float2 tv = TAB[lc];
      const float r  = f0 * tv.x;
      const float fr = r - floorf(r);                  // fractional revolutions
      const float sv = __builtin_amdgcn_sinf(fr);      // sin(2*pi*fr)
      const float cw = ((unsigned)l < (unsigned)kGrainN) ? c * tv.y : 0.0f;
      if (k == 0) a0 = fmaf(cw, sv, a0);
      else if (k == 1) a1 = fmaf(cw, sv, a1);
      else if (k == 2) a2 = fmaf(cw, sv, a2);
      else a3 = fmaf(cw, sv, a3);
    }
  }

  out[base]       = a0;
  out[base + 256] = a1;
  out[base + 512] = a2;
  out[base + 768] = a3;

  // fused per-tile sum of squares (f64)
  double p2 = (double)a0 * a0 + (double)a1 * a1 + (double)a2 * a2 + (double)a3 * a3;
  for (int off = 32; off > 0; off >>= 1) p2 += __shfl_down(p2, off);
  __shared__ double wpart[4];
  if ((tid & 63) == 0) wpart[tid >> 6] = p2;
  __syncthreads();
  if (tid == 0) partials[tile] = wpart[0] + wpart[1] + wpart[2] + wpart[3];
}

// Kernel 4: reduce partials -> 1/sqrt(sum)
__global__ __launch_bounds__(256) void k_final(void* wsv) {
  char* ws = (char*)wsv;
  const double* __restrict__ partials = (const double*)(ws + PART_OFF);
  __shared__ double red[256];
  const int tid = threadIdx.x;
  double sum = 0.0;
  for (int t = tid; t < kNTiles; t += 256) sum += partials[t];
  red[tid] = sum;
  __syncthreads();
  for (int s = 128; s > 0; s >>= 1) {
    if (tid < s) red[tid] += red[tid + s];
    __syncthreads();
  }
  if (tid == 0) *(double*)(ws + SCALE_OFF) = 1.0 / sqrt(red[0]);
}

// Kernel 5: scale output by 1/norm (float4)
__global__ __launch_bounds__(256) void k_scale(const void* wsv, float4* __restrict__ out) {
  const float sc = (float)(*(const double*)((const char*)wsv + SCALE_OFF));
  const int i = blockIdx.x * 256 + threadIdx.x;
  float4 v = out[i];
  v.x *= sc; v.y *= sc; v.z *= sc; v.w *= sc;
  out[i] = v;
}

extern "C" void kernel_launch(void* const* d_in, const int* in_sizes, int n_in,
                              void* d_out, int out_size, void* d_ws, size_t ws_size,
                              hipStream_t stream) {
  const float* dens   = (const float*)d_in[0];
  const float* slope  = (const float*)d_in[1];
  const float* f0     = (const float*)d_in[2];
  const int*   onsets = (const int*)d_in[3];
  float* out = (float*)d_out;

  hipLaunchKernelGGL(k_prep,   dim3(64), dim3(256), 0, stream, dens, f0, onsets, d_ws);
  hipLaunchKernelGGL(k_tables, dim3(kGrainN / 256), dim3(256), 0, stream, slope, d_ws);
  hipLaunchKernelGGL(k_main,   dim3(kNTiles), dim3(256), 0, stream, d_ws, out);
  hipLaunchKernelGGL(k_final,  dim3(1), dim3(256), 0, stream, d_ws);
  hipLaunchKernelGGL(k_scale,  dim3(kNSamples / 1024), dim3(256), 0, stream, d_ws,
                     (float4*)out);
}

// Round 5
// 75.283 us; speedup vs baseline: 1.8726x; 1.1166x over previous
//
#include <hip/hip_runtime.h>
#include <math.h>

#ifndef M_PI
#define M_PI 3.14159265358979323846
#endif

namespace {
constexpr int kNSamples = 524288;
constexpr int kNGrains  = 4096;
constexpr int kGrainN   = 16384;
constexpr int kTile     = 512;                  // 2 samples/thread * 256 threads
constexpr int kNTiles   = kNSamples / kTile;    // 1024 blocks -> 4/CU
constexpr int kGuard    = 1024;                 // guard entries each side (w2=0)
constexpr int kTabN     = kGrainN + 2 * kGuard; // 18432

// ws layout (bytes), all 16-aligned
constexpr size_t PART_OFF  = 0;                            // double[kNTiles]      8 KB
constexpr size_t ONS_OFF   = PART_OFF + 8 * kNTiles;       // int[kNGrains]       16 KB
constexpr size_t GR_OFF    = ONS_OFF + 4 * kNGrains;       // float4[kNGrains]    64 KB
constexpr size_t TAB_OFF   = GR_OFF + 16 * kNGrains;       // float2[kTabN]      144 KB
constexpr size_t SCALE_OFF = TAB_OFF + 8 * kTabN;          // double
// end = SCALE_OFF + 8 = 237,576 bytes
}  // namespace

// Kernel 1 (parallel rank sort + per-grain coefs):
// 64 blocks x 256 threads. Block b owns grains [b*64, b*64+64).
// rank[g] = #{h : (onset[h], h) < (onset[g], g)} -- strict total order,
// deterministic, no atomics. max(amps) == amps[0] (amps strictly decreasing).
__global__ __launch_bounds__(256) void k_prep(const float* __restrict__ dens_p,
                                              const float* __restrict__ f0,
                                              const int* __restrict__ onsets,
                                              void* wsv) {
  char* ws = (char*)wsv;
  __shared__ int sons[kNGrains];        // 16 KB
  __shared__ int srank[64][5];          // padded
  const int tid = threadIdx.x;

  for (int i = tid; i < kNGrains; i += 256) sons[i] = onsets[i];
  __syncthreads();

  const int gi = tid & 63;
  const int g  = blockIdx.x * 64 + gi;
  const int ck = tid >> 6;              // 0..3
  const int og = sons[g];

  int pr = 0;
  const int h0 = ck * 1024;
#pragma unroll 8
  for (int h = h0; h < h0 + 1024; ++h) {
    const int oh = sons[h];
    pr += (int)(oh < og) | ((int)(oh == og) & (int)(h < g));
  }
  srank[gi][ck] = pr;
  __syncthreads();

  if (tid < 64) {
    const int gg   = blockIdx.x * 64 + tid;
    const int rank = srank[tid][0] + srank[tid][1] + srank[tid][2] + srank[tid][3];

    const double d      = (double)dens_p[0];
    const double offset = 0.25 * d + 0.75 * d * d;
    const double c2     = 2.0 * (1.0 - d) * 4096.0;
    const double amp    = 1.0 / (1.0 + exp(c2 * ((double)gg / 4096.0 - offset)));
    const double amp0   = 1.0 / (1.0 + exp(c2 * (0.0 - offset)));  // max amp

    const float f0g = f0[gg];
    const float cg  = (float)(amp / amp0) / sqrtf(f0g);
    ((int*)(ws + ONS_OFF))[rank] = sons[gg];
    ((float4*)(ws + GR_OFF))[rank] =
        make_float4(__int_as_float(sons[gg]), f0g, cg, 0.0f);
  }
}

// Kernel 2: guard-padded table, f64 -> f32.
// Entry e corresponds to l = e - kGuard. In-range: {phase_l, sin^2(pi*l/L)};
// guards: {0, 0} (w2=0 annihilates the contribution, phase value irrelevant).
__global__ __launch_bounds__(256) void k_tables(const float* __restrict__ slope_p,
                                                void* wsv) {
  char* ws = (char*)wsv;
  const int e = blockIdx.x * 256 + threadIdx.x;
  const int l = e - kGuard;
  float2 v = make_float2(0.0f, 0.0f);
  if ((unsigned)l < (unsigned)kGrainN) {
    const double ts    = (double)slope_p[0];
    const double gamma = tan(ts * M_PI / 2.0) * (44100.0 / (12.0 * 256.0)) / 4.0;
    const float  tf    = (float)l / 44100.0f - 0.18575963718820862f;  // ref f32 t
    double ph;
    if (gamma == 0.0) ph = (double)tf;
    else              ph = expm1(gamma * (double)tf) / gamma;
    const double wv = sin(M_PI * ((double)l / 16384.0));
    v = make_float2((float)ph, (float)(wv * wv));
  }
  ((float2*)(ws + TAB_OFF))[e] = v;
}

// Kernel 3: output-stationary accumulation, all-f32, next-grain prefetch.
__global__ __launch_bounds__(256) void k_main(void* wsv, float* __restrict__ out) {
  char* ws = (char*)wsv;
  const int*    __restrict__ ons = (const int*)(ws + ONS_OFF);
  const float4* __restrict__ GR  = (const float4*)(ws + GR_OFF);
  const float2* __restrict__ TAB = (const float2*)(ws + TAB_OFF);
  double* __restrict__ partials  = (double*)(ws + PART_OFF);

  const int tile = blockIdx.x;
  const int s    = tile * kTile;
  const int tid  = threadIdx.x;

  // grains overlapping [s, s+kTile): onset in (s - kGrainN, s + kTile - 1]
  int lo, hi;
  {
    int a = 0, b = kNGrains;
    const int t1 = s - kGrainN;
    while (a < b) { int mid = (a + b) >> 1; if (ons[mid] > t1) b = mid; else a = mid + 1; }
    lo = a;
    a = lo; b = kNGrains;
    const int t2 = s + kTile - 1;
    while (a < b) { int mid = (a + b) >> 1; if (ons[mid] > t2) b = mid; else a = mid + 1; }
    hi = a;
  }
  lo = __builtin_amdgcn_readfirstlane(lo);
  hi = __builtin_amdgcn_readfirstlane(hi);

  float a0 = 0.0f, a1 = 0.0f;
  const int b0 = s + tid + kGuard;   // padded-table base index for sample 0
  const int b1 = b0 + 256;           // sample 1

  if (lo < hi) {
    float4 gr  = GR[lo];
    float4 grn = GR[min(lo + 1, hi - 1)];
    int    on0 = __float_as_int(gr.x);
    float2 tv0 = TAB[b0 - on0];
    float2 tv1 = TAB[b1 - on0];

    for (int g = lo; g < hi; ++g) {
      // prefetch grain g+1's table entries (indices uniform-clamped to hi-1)
      const int onn = __float_as_int(grn.x);
      const float2 nt0 = TAB[b0 - onn];
      const float2 nt1 = TAB[b1 - onn];
      const float4 gr2 = GR[min(g + 2, hi - 1)];

      const float f0 = gr.y;
      const float c  = gr.z;
      const float r0 = f0 * tv0.x;
      const float r1 = f0 * tv1.x;
      a0 = fmaf(c * tv0.y, __builtin_amdgcn_sinf(__builtin_amdgcn_fractf(r0)), a0);
      a1 = fmaf(c * tv1.y, __builtin_amdgcn_sinf(__builtin_amdgcn_fractf(r1)), a1);

      tv0 = nt0; tv1 = nt1; gr = grn; grn = gr2;
    }
  }

  out[s + tid]       = a0;
  out[s + tid + 256] = a1;

  // fused per-tile sum of squares (f64)
  double p2 = (double)a0 * a0 + (double)a1 * a1;
  for (int off = 32; off > 0; off >>= 1) p2 += __shfl_down(p2, off);
  __shared__ double wpart[4];
  if ((tid & 63) == 0) wpart[tid >> 6] = p2;
  __syncthreads();
  if (tid == 0) partials[tile] = wpart[0] + wpart[1] + wpart[2] + wpart[3];
}

// Kernel 4: reduce partials -> 1/sqrt(sum)
__global__ __launch_bounds__(256) void k_final(void* wsv) {
  char* ws = (char*)wsv;
  const double* __restrict__ partials = (const double*)(ws + PART_OFF);
  __shared__ double red[256];
  const int tid = threadIdx.x;
  double sum = 0.0;
  for (int t = tid; t < kNTiles; t += 256) sum += partials[t];
  red[tid] = sum;
  __syncthreads();
  for (int s = 128; s > 0; s >>= 1) {
    if (tid < s) red[tid] += red[tid + s];
    __syncthreads();
  }
  if (tid == 0) *(double*)(ws + SCALE_OFF) = 1.0 / sqrt(red[0]);
}

// Kernel 5: scale output by 1/norm (float4)
__global__ __launch_bounds__(256) void k_scale(const void* wsv, float4* __restrict__ out) {
  const float sc = (float)(*(const double*)((const char*)wsv + SCALE_OFF));
  const int i = blockIdx.x * 256 + threadIdx.x;
  float4 v = out[i];
  v.x *= sc; v.y *= sc; v.z *= sc; v.w *= sc;
  out[i] = v;
}

extern "C" void kernel_launch(void* const* d_in, const int* in_sizes, int n_in,
                              void* d_out, int out_size, void* d_ws, size_t ws_size,
                              hipStream_t stream) {
  const float* dens   = (const float*)d_in[0];
  const float* slope  = (const float*)d_in[1];
  const float* f0     = (const float*)d_in[2];
  const int*   onsets = (const int*)d_in[3];
  float* out = (float*)d_out;

  hipLaunchKernelGGL(k_prep,   dim3(64), dim3(256), 0, stream, dens, f0, onsets, d_ws);
  hipLaunchKernelGGL(k_tables, dim3(kTabN / 256), dim3(256), 0, stream, slope, d_ws);
  hipLaunchKernelGGL(k_main,   dim3(kNTiles), dim3(256), 0, stream, d_ws, out);
  hipLaunchKernelGGL(k_final,  dim3(1), dim3(256), 0, stream, d_ws);
  hipLaunchKernelGGL(k_scale,  dim3(kNSamples / 1024), dim3(256), 0, stream, d_ws,
                     (float4*)out);
}

// Round 6
// 71.534 us; speedup vs baseline: 1.9707x; 1.0524x over previous
//
#include <hip/hip_runtime.h>
#include <math.h>

#ifndef M_PI
#define M_PI 3.14159265358979323846
#endif

namespace {
constexpr int kNSamples = 524288;
constexpr int kNGrains  = 4096;
constexpr int kGrainN   = 16384;
constexpr int kTile     = 512;                  // 2 samples/thread * 256 threads
constexpr int kNTiles   = kNSamples / kTile;    // 1024 blocks -> 4/CU
constexpr int kGuard    = 1024;                 // guard entries each side (phase=0)
constexpr int kTabN     = kGrainN + 2 * kGuard; // 18432

// ws layout (bytes), all 16-aligned
constexpr size_t PART_OFF  = 0;                            // double[kNTiles]      8 KB
constexpr size_t ONS_OFF   = PART_OFF + 8 * kNTiles;       // int[kNGrains]       16 KB
constexpr size_t GR_OFF    = ONS_OFF + 4 * kNGrains;       // float4[kNGrains]    64 KB
constexpr size_t TAB_OFF   = GR_OFF + 16 * kNGrains;       // float[kTabN]        72 KB
constexpr size_t SCALE_OFF = TAB_OFF + 4 * kTabN;          // double
// end = SCALE_OFF + 8 = 163,848 bytes
}  // namespace

// Fused setup kernel. Blocks [0,64): rank-sort + per-grain coefs.
// Blocks [64, 64+72): phase table (f64 -> f32), guards = 0.
//
// rank[g] = #{h : (onset[h], h) < (onset[g], g)} -- strict total order,
// deterministic, no atomics. max(amps) == amps[0] (amps strictly decreasing).
// Guard phase 0 => sin(2*pi*f0*0) = 0 => OOB contributions vanish w/o a mask.
__global__ __launch_bounds__(256) void k_setup(const float* __restrict__ dens_p,
                                               const float* __restrict__ slope_p,
                                               const float* __restrict__ f0,
                                               const int* __restrict__ onsets,
                                               void* wsv) {
  char* ws = (char*)wsv;
  const int tid = threadIdx.x;

  if (blockIdx.x >= 64) {
    // ---- phase table ----
    const int e = (blockIdx.x - 64) * 256 + tid;
    const int l = e - kGuard;
    float v = 0.0f;
    if ((unsigned)l < (unsigned)kGrainN) {
      const double ts    = (double)slope_p[0];
      const double gamma = tan(ts * M_PI / 2.0) * (44100.0 / (12.0 * 256.0)) / 4.0;
      const float  tf    = (float)l / 44100.0f - 0.18575963718820862f;  // ref f32 t
      double ph;
      if (gamma == 0.0) ph = (double)tf;
      else              ph = expm1(gamma * (double)tf) / gamma;
      v = (float)ph;
    }
    ((float*)(ws + TAB_OFF))[e] = v;
    return;
  }

  // ---- rank sort + coefs ----
  __shared__ int sons[kNGrains];        // 16 KB
  __shared__ int srank[64][5];          // padded

  for (int i = tid; i < kNGrains; i += 256) sons[i] = onsets[i];
  __syncthreads();

  const int gi = tid & 63;
  const int g  = blockIdx.x * 64 + gi;
  const int ck = tid >> 6;              // 0..3
  const int og = sons[g];

  int pr = 0;
  const int h0 = ck * 1024;
#pragma unroll 8
  for (int h = h0; h < h0 + 1024; ++h) {
    const int oh = sons[h];
    pr += (int)(oh < og) | ((int)(oh == og) & (int)(h < g));
  }
  srank[gi][ck] = pr;
  __syncthreads();

  if (tid < 64) {
    const int gg   = blockIdx.x * 64 + tid;
    const int rank = srank[tid][0] + srank[tid][1] + srank[tid][2] + srank[tid][3];

    const double d      = (double)dens_p[0];
    const double offset = 0.25 * d + 0.75 * d * d;
    const double c2     = 2.0 * (1.0 - d) * 4096.0;
    const double amp    = 1.0 / (1.0 + exp(c2 * ((double)gg / 4096.0 - offset)));
    const double amp0   = 1.0 / (1.0 + exp(c2 * (0.0 - offset)));  // max amp

    const float f0g = f0[gg];
    const float cg  = (float)(amp / amp0) / sqrtf(f0g);
    ((int*)(ws + ONS_OFF))[rank] = sons[gg];
    ((float4*)(ws + GR_OFF))[rank] =
        make_float4(__int_as_float(sons[gg]), f0g, cg, 0.0f);
  }
}

// Main kernel: output-stationary, all-f32, phase-only table, on-the-fly window,
// uniform (SALU) per-grain table base, depth-2 load pipeline.
__global__ __launch_bounds__(256) void k_main(const int* __restrict__ ons,
                                              const float4* __restrict__ GR,
                                              const float* __restrict__ TABF,
                                              double* __restrict__ partials,
                                              float* __restrict__ out) {
  const int tile = blockIdx.x;
  const int s    = tile * kTile;
  const int tid  = threadIdx.x;

  // grains overlapping [s, s+kTile): onset in (s - kGrainN, s + kTile - 1]
  int lo, hi;
  {
    int a = 0, b = kNGrains;
    const int t1 = s - kGrainN;
    while (a < b) { int mid = (a + b) >> 1; if (ons[mid] > t1) b = mid; else a = mid + 1; }
    lo = a;
    a = lo; b = kNGrains;
    const int t2 = s + kTile - 1;
    while (a < b) { int mid = (a + b) >> 1; if (ons[mid] > t2) b = mid; else a = mid + 1; }
    hi = a;
  }
  lo = __builtin_amdgcn_readfirstlane(lo);
  hi = __builtin_amdgcn_readfirstlane(hi);

  float a0 = 0.0f, a1 = 0.0f;
  const int p0 = s + tid;            // sample index of eval 0 (eval 1 = +256)
  const float* TABG = TABF + kGuard; // guarded origin (uniform)

  if (lo < hi) {
    const int last = hi - 1;
    float4 gA = GR[lo];
    float4 gB = GR[lo + 1 <= last ? lo + 1 : last];
    int   onA = __float_as_int(gA.x);
    int   onB = __float_as_int(gB.x);
    const float* pA = TABG - onA;    // uniform base; loads use voffset p0
    const float* pB = TABG - onB;
    float tA0 = pA[p0], tA1 = pA[p0 + 256];
    float tB0 = pB[p0], tB1 = pB[p0 + 256];

    for (int g = lo; g < hi; ++g) {
      // issue grain g+2's loads (depth-2 pipeline)
      const float4 gC = GR[g + 2 <= last ? g + 2 : last];
      const int   onC = __float_as_int(gC.x);
      const float* pC = TABG - onC;
      const float tC0 = pC[p0], tC1 = pC[p0 + 256];

      // compute grain g
      const float f0 = gA.y, c = gA.z;
      const float lf   = (float)(p0 - onA);
      const float arg0 = lf * (1.0f / 16384.0f);
      const float arg1 = arg0 + (256.0f / 16384.0f);
      const float sv0  = __builtin_amdgcn_sinf(__builtin_amdgcn_fractf(f0 * tA0));
      const float sv1  = __builtin_amdgcn_sinf(__builtin_amdgcn_fractf(f0 * tA1));
      const float w20  = fmaf(-0.5f, __builtin_amdgcn_cosf(arg0), 0.5f);
      const float w21  = fmaf(-0.5f, __builtin_amdgcn_cosf(arg1), 0.5f);
      a0 = fmaf(c * w20, sv0, a0);
      a1 = fmaf(c * w21, sv1, a1);

      // rotate pipeline
      gA = gB; onA = onB; tA0 = tB0; tA1 = tB1;
      gB = gC; onB = onC; tB0 = tC0; tB1 = tC1;
    }
  }

  out[p0]       = a0;
  out[p0 + 256] = a1;

  // fused per-tile sum of squares (f64)
  double p2 = (double)a0 * a0 + (double)a1 * a1;
  for (int off = 32; off > 0; off >>= 1) p2 += __shfl_down(p2, off);
  __shared__ double wpart[4];
  if ((tid & 63) == 0) wpart[tid >> 6] = p2;
  __syncthreads();
  if (tid == 0) partials[tile] = wpart[0] + wpart[1] + wpart[2] + wpart[3];
}

// Reduce partials -> 1/sqrt(sum)
__global__ __launch_bounds__(256) void k_final(void* wsv) {
  char* ws = (char*)wsv;
  const double* __restrict__ partials = (const double*)(ws + PART_OFF);
  __shared__ double red[256];
  const int tid = threadIdx.x;
  double sum = 0.0;
  for (int t = tid; t < kNTiles; t += 256) sum += partials[t];
  red[tid] = sum;
  __syncthreads();
  for (int s = 128; s > 0; s >>= 1) {
    if (tid < s) red[tid] += red[tid + s];
    __syncthreads();
  }
  if (tid == 0) *(double*)(ws + SCALE_OFF) = 1.0 / sqrt(red[0]);
}

// Scale output by 1/norm (float4)
__global__ __launch_bounds__(256) void k_scale(const void* wsv, float4* __restrict__ out) {
  const float sc = (float)(*(const double*)((const char*)wsv + SCALE_OFF));
  const int i = blockIdx.x * 256 + threadIdx.x;
  float4 v = out[i];
  v.x *= sc; v.y *= sc; v.z *= sc; v.w *= sc;
  out[i] = v;
}

extern "C" void kernel_launch(void* const* d_in, const int* in_sizes, int n_in,
                              void* d_out, int out_size, void* d_ws, size_t ws_size,
                              hipStream_t stream) {
  const float* dens   = (const float*)d_in[0];
  const float* slope  = (const float*)d_in[1];
  const float* f0     = (const float*)d_in[2];
  const int*   onsets = (const int*)d_in[3];
  float* out = (float*)d_out;
  char*  ws  = (char*)d_ws;

  hipLaunchKernelGGL(k_setup, dim3(64 + kTabN / 256), dim3(256), 0, stream,
                     dens, slope, f0, onsets, d_ws);
  hipLaunchKernelGGL(k_main, dim3(kNTiles), dim3(256), 0, stream,
                     (const int*)(ws + ONS_OFF), (const float4*)(ws + GR_OFF),
                     (const float*)(ws + TAB_OFF), (double*)(ws + PART_OFF), out);
  hipLaunchKernelGGL(k_final, dim3(1), dim3(256), 0, stream, d_ws);
  hipLaunchKernelGGL(k_scale, dim3(kNSamples / 1024), dim3(256), 0, stream, d_ws,
                     (float4*)out);
}